// Round 8
// baseline (953.723 us; speedup 1.0000x reference)
//
#include <hip/hip_runtime.h>

#define T_STEPS 512
#define HS 20       // hidden size
#define F0 10       // input features (layer 0)
#define BPB 6       // batches per block: lane-group g handles batches {g, g+3}
#define NB_TOT 4096
#define NBLK ((NB_TOT + BPB - 1) / BPB)   // 683

__device__ __forceinline__ float sigmoid_fast(float v) {
    return __fdividef(1.f, 1.f + __expf(-v));
}
__device__ __forceinline__ float tanh_fast(float v) {
    return 1.f - __fdividef(2.f, __expf(2.f * v) + 1.f);
}
#define PIN(v) asm volatile("" : "+v"(v))

// R7 structure (layer-split waves, skew-1 pipeline, 6 batches/block, one
// dispatch round) + R8 change: h-recurrence weights (whh0 / whh1, 80
// floats/lane) move to LDS [80][20] (rows 80 B, 16B-aligned, ~2.5-way bank
// aliasing = near-free). Register weights drop to max 84/lane -> the whole
// working set fits in ARCH VGPRs at (128,2); kills the v_accvgpr_read tax
// that inflated R7's VALU stream (~136 extra insts/wave/iter).
__global__ __launch_bounds__(128, 2)
void lstm2_fc_kernel(const float* __restrict__ x,
                     const float* __restrict__ wih0, const float* __restrict__ whh0,
                     const float* __restrict__ bih0, const float* __restrict__ bhh0,
                     const float* __restrict__ wih1, const float* __restrict__ whh1,
                     const float* __restrict__ bih1, const float* __restrict__ bhh1,
                     const float* __restrict__ wfc,  const float* __restrict__ bfc,
                     float* __restrict__ out)
{
    const int tid  = threadIdx.x;
    const int wid  = tid >> 6;
    const int lane = tid & 63;
    const int g    = (lane / HS) % 3;   // lanes 60..63 shadow group 0 (benign dups)
    const int u    = lane % HS;
    const int bgA  = blockIdx.x * BPB + g;          // always < 4096
    const int bgBr = blockIdx.x * BPB + g + 3;
    const bool okB = (bgBr < NB_TOT);
    const int bgB  = okB ? bgBr : (NB_TOT - 1);     // clamp reads

    __shared__ float s_h0[2][BPB][HS];   // double buffer: wave0 -> wave1
    __shared__ float s_h1[BPB][HS];      // wave1-private recurrence state
    __shared__ float s_w0[4 * HS * HS];  // whh0, rows of 20 floats (80 B, 16B-aligned)
    __shared__ float s_w1[4 * HS * HS];  // whh1, same layout

    for (int i = tid; i < 2 * BPB * HS; i += 128) (&s_h0[0][0][0])[i] = 0.f;
    for (int i = tid; i < BPB * HS; i += 128)     (&s_h1[0][0])[i]    = 0.f;
    for (int i = tid; i < 4 * HS * HS; i += 128) {
        s_w0[i] = whh0[i];
        s_w1[i] = whh1[i];
    }

    // ---- per-lane REGISTER weights: input-projection rows only ----
    // wave0: w[q][0..9]  = wih0 row q*HS+u   (10 used)
    // wave1: w[q][0..19] = wih1 row q*HS+u   (20 used)
    float w[4][HS], bias[4];
    if (wid == 0) {
        #pragma unroll
        for (int q = 0; q < 4; ++q) {
            const int row = q * HS + u;
            #pragma unroll
            for (int f = 0; f < F0; ++f) { w[q][f] = wih0[row * F0 + f]; PIN(w[q][f]); }
            bias[q] = bih0[row] + bhh0[row]; PIN(bias[q]);
        }
    } else {
        #pragma unroll
        for (int q = 0; q < 4; ++q) {
            const int row = q * HS + u;
            #pragma unroll
            for (int j = 0; j < HS; ++j) { w[q][j] = wih1[row * HS + j]; PIN(w[q][j]); }
            bias[q] = bih1[row] + bhh1[row]; PIN(bias[q]);
        }
    }

    // LDS row base for this lane's 4 recurrence-weight rows (row = q*HS+u)
    const float* wr = (wid == 0) ? s_w0 : s_w1;
    const float* wrow0 = wr + (0 * HS + u) * HS;
    const float* wrow1 = wr + (1 * HS + u) * HS;
    const float* wrow2 = wr + (2 * HS + u) * HS;
    const float* wrow3 = wr + (3 * HS + u) * HS;

    float cA = 0.f, cB = 0.f;
    const float* xbA = x + (size_t)bgA * (T_STEPS * F0);
    const float* xbB = x + (size_t)bgB * (T_STEPS * F0);

    __syncthreads();

    for (int t = 0; t <= T_STEPS; ++t) {
        if (wid == 0) {
            if (t < T_STEPS) {
                float xA[F0], xB[F0];
                {
                    const float2* pA = (const float2*)(xbA + t * F0);
                    const float2* pB = (const float2*)(xbB + t * F0);
                    #pragma unroll
                    for (int f = 0; f < F0 / 2; ++f) {
                        float2 vA = pA[f], vB = pB[f];
                        xA[2*f] = vA.x; xA[2*f+1] = vA.y;
                        xB[2*f] = vB.x; xB[2*f+1] = vB.y;
                    }
                }
                float aA0 = bias[0], aA1 = bias[1], aA2 = bias[2], aA3 = bias[3];
                float aB0 = bias[0], aB1 = bias[1], aB2 = bias[2], aB3 = bias[3];
                const float* hpA = &s_h0[(t + 1) & 1][g][0];       // h0(t-1)
                const float* hpB = &s_h0[(t + 1) & 1][g + 3][0];
                #pragma unroll
                for (int q4 = 0; q4 < HS / 4; ++q4) {
                    const float4 hA = *(const float4*)(hpA + 4 * q4);
                    const float4 hB = *(const float4*)(hpB + 4 * q4);
                    const float4 w0 = *(const float4*)(wrow0 + 4 * q4);  // whh0 rows (LDS)
                    const float4 w1 = *(const float4*)(wrow1 + 4 * q4);
                    const float4 w2 = *(const float4*)(wrow2 + 4 * q4);
                    const float4 w3 = *(const float4*)(wrow3 + 4 * q4);
                    aA0 = fmaf(hA.x, w0.x, aA0);  aB0 = fmaf(hB.x, w0.x, aB0);
                    aA1 = fmaf(hA.x, w1.x, aA1);  aB1 = fmaf(hB.x, w1.x, aB1);
                    aA2 = fmaf(hA.x, w2.x, aA2);  aB2 = fmaf(hB.x, w2.x, aB2);
                    aA3 = fmaf(hA.x, w3.x, aA3);  aB3 = fmaf(hB.x, w3.x, aB3);
                    aA0 = fmaf(hA.y, w0.y, aA0);  aB0 = fmaf(hB.y, w0.y, aB0);
                    aA1 = fmaf(hA.y, w1.y, aA1);  aB1 = fmaf(hB.y, w1.y, aB1);
                    aA2 = fmaf(hA.y, w2.y, aA2);  aB2 = fmaf(hB.y, w2.y, aB2);
                    aA3 = fmaf(hA.y, w3.y, aA3);  aB3 = fmaf(hB.y, w3.y, aB3);
                    aA0 = fmaf(hA.z, w0.z, aA0);  aB0 = fmaf(hB.z, w0.z, aB0);
                    aA1 = fmaf(hA.z, w1.z, aA1);  aB1 = fmaf(hB.z, w1.z, aB1);
                    aA2 = fmaf(hA.z, w2.z, aA2);  aB2 = fmaf(hB.z, w2.z, aB2);
                    aA3 = fmaf(hA.z, w3.z, aA3);  aB3 = fmaf(hB.z, w3.z, aB3);
                    aA0 = fmaf(hA.w, w0.w, aA0);  aB0 = fmaf(hB.w, w0.w, aB0);
                    aA1 = fmaf(hA.w, w1.w, aA1);  aB1 = fmaf(hB.w, w1.w, aB1);
                    aA2 = fmaf(hA.w, w2.w, aA2);  aB2 = fmaf(hB.w, w2.w, aB2);
                    aA3 = fmaf(hA.w, w3.w, aA3);  aB3 = fmaf(hB.w, w3.w, aB3);
                }
                #pragma unroll
                for (int f = 0; f < F0; ++f) {
                    aA0 = fmaf(xA[f], w[0][f], aA0);  aB0 = fmaf(xB[f], w[0][f], aB0);
                    aA1 = fmaf(xA[f], w[1][f], aA1);  aB1 = fmaf(xB[f], w[1][f], aB1);
                    aA2 = fmaf(xA[f], w[2][f], aA2);  aB2 = fmaf(xB[f], w[2][f], aB2);
                    aA3 = fmaf(xA[f], w[3][f], aA3);  aB3 = fmaf(xB[f], w[3][f], aB3);
                }
                {
                    const float iA = sigmoid_fast(aA0), fA = sigmoid_fast(aA1);
                    const float gA = tanh_fast(aA2),    oA = sigmoid_fast(aA3);
                    cA = fA * cA + iA * gA;
                    s_h0[t & 1][g][u] = oA * tanh_fast(cA);
                    const float iB = sigmoid_fast(aB0), fB = sigmoid_fast(aB1);
                    const float gB = tanh_fast(aB2),    oB = sigmoid_fast(aB3);
                    cB = fB * cB + iB * gB;
                    s_h0[t & 1][g + 3][u] = oB * tanh_fast(cB);
                }
            }
        } else {
            if (t >= 1) {
                // layer1 computes step s = t-1
                float aA0 = bias[0], aA1 = bias[1], aA2 = bias[2], aA3 = bias[3];
                float aB0 = bias[0], aB1 = bias[1], aB2 = bias[2], aB3 = bias[3];
                const float* hpA = &s_h0[(t - 1) & 1][g][0];       // h0(s)
                const float* hpB = &s_h0[(t - 1) & 1][g + 3][0];
                #pragma unroll
                for (int q4 = 0; q4 < HS / 4; ++q4) {
                    const float4 hA = *(const float4*)(hpA + 4 * q4);
                    const float4 hB = *(const float4*)(hpB + 4 * q4);
                    const float eA[4] = {hA.x, hA.y, hA.z, hA.w};
                    const float eB[4] = {hB.x, hB.y, hB.z, hB.w};
                    #pragma unroll
                    for (int s = 0; s < 4; ++s) {
                        const int k = 4 * q4 + s;
                        aA0 = fmaf(eA[s], w[0][k], aA0);  aB0 = fmaf(eB[s], w[0][k], aB0);
                        aA1 = fmaf(eA[s], w[1][k], aA1);  aB1 = fmaf(eB[s], w[1][k], aB1);
                        aA2 = fmaf(eA[s], w[2][k], aA2);  aB2 = fmaf(eB[s], w[2][k], aB2);
                        aA3 = fmaf(eA[s], w[3][k], aA3);  aB3 = fmaf(eB[s], w[3][k], aB3);
                    }
                }
                const float* ppA = &s_h1[g][0];                    // h1(s-1)
                const float* ppB = &s_h1[g + 3][0];
                #pragma unroll
                for (int q4 = 0; q4 < HS / 4; ++q4) {
                    const float4 hA = *(const float4*)(ppA + 4 * q4);
                    const float4 hB = *(const float4*)(ppB + 4 * q4);
                    const float4 w0 = *(const float4*)(wrow0 + 4 * q4);  // whh1 rows (LDS)
                    const float4 w1 = *(const float4*)(wrow1 + 4 * q4);
                    const float4 w2 = *(const float4*)(wrow2 + 4 * q4);
                    const float4 w3 = *(const float4*)(wrow3 + 4 * q4);
                    aA0 = fmaf(hA.x, w0.x, aA0);  aB0 = fmaf(hB.x, w0.x, aB0);
                    aA1 = fmaf(hA.x, w1.x, aA1);  aB1 = fmaf(hB.x, w1.x, aB1);
                    aA2 = fmaf(hA.x, w2.x, aA2);  aB2 = fmaf(hB.x, w2.x, aB2);
                    aA3 = fmaf(hA.x, w3.x, aA3);  aB3 = fmaf(hB.x, w3.x, aB3);
                    aA0 = fmaf(hA.y, w0.y, aA0);  aB0 = fmaf(hB.y, w0.y, aB0);
                    aA1 = fmaf(hA.y, w1.y, aA1);  aB1 = fmaf(hB.y, w1.y, aB1);
                    aA2 = fmaf(hA.y, w2.y, aA2);  aB2 = fmaf(hB.y, w2.y, aB2);
                    aA3 = fmaf(hA.y, w3.y, aA3);  aB3 = fmaf(hB.y, w3.y, aB3);
                    aA0 = fmaf(hA.z, w0.z, aA0);  aB0 = fmaf(hB.z, w0.z, aB0);
                    aA1 = fmaf(hA.z, w1.z, aA1);  aB1 = fmaf(hB.z, w1.z, aB1);
                    aA2 = fmaf(hA.z, w2.z, aA2);  aB2 = fmaf(hB.z, w2.z, aB2);
                    aA3 = fmaf(hA.z, w3.z, aA3);  aB3 = fmaf(hB.z, w3.z, aB3);
                    aA0 = fmaf(hA.w, w0.w, aA0);  aB0 = fmaf(hB.w, w0.w, aB0);
                    aA1 = fmaf(hA.w, w1.w, aA1);  aB1 = fmaf(hB.w, w1.w, aB1);
                    aA2 = fmaf(hA.w, w2.w, aA2);  aB2 = fmaf(hB.w, w2.w, aB2);
                    aA3 = fmaf(hA.w, w3.w, aA3);  aB3 = fmaf(hB.w, w3.w, aB3);
                }
                const float iA = sigmoid_fast(aA0), fA = sigmoid_fast(aA1);
                const float gA = tanh_fast(aA2),    oA = sigmoid_fast(aA3);
                const float iB = sigmoid_fast(aB0), fB = sigmoid_fast(aB1);
                const float gB = tanh_fast(aB2),    oB = sigmoid_fast(aB3);
                cA = fA * cA + iA * gA;
                cB = fB * cB + iB * gB;
                __builtin_amdgcn_wave_barrier();   // h1(s-1) reads precede writes
                s_h1[g][u]     = oA * tanh_fast(cA);
                s_h1[g + 3][u] = oB * tanh_fast(cB);
            }
        }
        __syncthreads();   // publish s_h0[t&1]; WAR-protect buffer reuse
    }

    // ---- final FC on h1(T-1) ----
    if (wid == 1 && lane < 60 && u == 0) {
        float oA = bfc[0], oB = bfc[0];
        #pragma unroll
        for (int j = 0; j < HS; ++j) {
            oA = fmaf(s_h1[g][j],     wfc[j], oA);
            oB = fmaf(s_h1[g + 3][j], wfc[j], oB);
        }
        out[bgA] = oA;
        if (okB) out[bgBr] = oB;
    }
}

extern "C" void kernel_launch(void* const* d_in, const int* in_sizes, int n_in,
                              void* d_out, int out_size, void* d_ws, size_t ws_size,
                              hipStream_t stream) {
    const float* x    = (const float*)d_in[0];
    const float* wih0 = (const float*)d_in[1];
    const float* whh0 = (const float*)d_in[2];
    const float* bih0 = (const float*)d_in[3];
    const float* bhh0 = (const float*)d_in[4];
    const float* wih1 = (const float*)d_in[5];
    const float* whh1 = (const float*)d_in[6];
    const float* bih1 = (const float*)d_in[7];
    const float* bhh1 = (const float*)d_in[8];
    const float* wfc  = (const float*)d_in[9];
    const float* bfc  = (const float*)d_in[10];
    float* out = (float*)d_out;

    dim3 grid(NBLK), block(128);
    hipLaunchKernelGGL(lstm2_fc_kernel, grid, block, 0, stream,
                       x, wih0, whh0, bih0, bhh0,
                       wih1, whh1, bih1, bhh1, wfc, bfc, out);
}